// Round 8
// baseline (832.505 us; speedup 1.0000x reference)
//
#include <hip/hip_runtime.h>
#include <cstdint>

#define SEQn   2048
#define NHn    16
#define HDn    128
#define DMn    2048   // NH*HD
#define HIDn   2048
#define BATCHn 2
#define WINn   256
#define MROWS  (BATCHn*SEQn)  // 4096
#define WELEMS ((size_t)HIDn * DMn)

typedef short s16x8 __attribute__((ext_vector_type(8)));  // 8 bf16 (4 VGPRs)
typedef float f32x4 __attribute__((ext_vector_type(4)));  // MFMA accumulator

__device__ __forceinline__ float bf2f(ushort x) {
    union { uint u; float f; } v; v.u = ((uint)x) << 16; return v.f;
}
__device__ __forceinline__ ushort f2bf(float f) {
    union { float f; uint u; } v; v.f = f;
    uint u = v.u;
    return (ushort)((u + 0x7FFFu + ((u >> 16) & 1u)) >> 16);  // RNE
}

// ---------------- x fp32 -> bf16 convert (coalesced, float4 in / ushort4 out)
__global__ __launch_bounds__(256)
void cvt_kernel(const float* __restrict__ src, ushort* __restrict__ dst)
{
    const int i = (blockIdx.x * 256 + threadIdx.x) * 4;
    const float4 v = *reinterpret_cast<const float4*>(src + i);
    ushort4 o;
    o.x = f2bf(v.x); o.y = f2bf(v.y); o.z = f2bf(v.z); o.w = f2bf(v.w);
    *reinterpret_cast<ushort4*>(dst + i) = o;
}

// --- batched transpose+convert: {WQ,WK,WV}[k][n] fp32 -> WT[z][n][k] bf16 ----
__global__ __launch_bounds__(256)
void transpose_qkv_kernel(const float* __restrict__ WQ, const float* __restrict__ WK,
                          const float* __restrict__ WV, ushort* __restrict__ WT)
{
    __shared__ ushort t[32][33];
    const float* src = (blockIdx.z == 0) ? WQ : (blockIdx.z == 1) ? WK : WV;
    ushort* dst = WT + (size_t)blockIdx.z * WELEMS;
    const int tx = threadIdx.x, ty = threadIdx.y;
    const int n  = blockIdx.x * 32 + tx;
    const int k0 = blockIdx.y * 32;
    #pragma unroll
    for (int r = ty; r < 32; r += 8)
        t[r][tx] = f2bf(src[(size_t)(k0 + r) * 2048 + n]);
    __syncthreads();
    const int k  = k0 + tx;
    const int nb = blockIdx.x * 32;
    #pragma unroll
    for (int r = ty; r < 32; r += 8)
        dst[(size_t)(nb + r) * 2048 + k] = t[tx][r];
}

// ------- single transpose+convert: W[k][n] fp32 -> WT[n][k] bf16 -------------
__global__ __launch_bounds__(256)
void transpose_cvt_kernel(const float* __restrict__ src, ushort* __restrict__ dst)
{
    __shared__ ushort t[32][33];
    const int tx = threadIdx.x, ty = threadIdx.y;
    const int n  = blockIdx.x * 32 + tx;
    const int k0 = blockIdx.y * 32;
    #pragma unroll
    for (int r = ty; r < 32; r += 8)
        t[r][tx] = f2bf(src[(size_t)(k0 + r) * 2048 + n]);
    __syncthreads();
    const int k  = k0 + tx;
    const int nb = blockIdx.x * 32;
    #pragma unroll
    for (int r = ty; r < 32; r += 8)
        dst[(size_t)(nb + r) * 2048 + k] = t[tx][r];
}

// -------- fused QKV GEMM + fused RoPE epilogue ------------------------------
// [Q|K|V](4096x6144) = x(4096x2048) * WT^T + bias.
// Software-pipelined K-loop: tile k+1 global->reg loads issued right after the
// staging barrier, latency hidden behind MFMA compute on tile k.
// Each block covers exactly ONE head (128 cols), so RoPE pairs (d, d+64) are
// intra-block: Q/K epilogue routes the C-tile through reused LDS, applies
// RoPE, writes coalesced. V epilogue scatters to Vt[b][h][d][s].
// C/D: col=lane&15, row=(lane>>4)*4+reg  (m89-verified mapping).
template<int ABF16>
__global__ __launch_bounds__(256)
void gemm_qkv_kernel(const void* __restrict__ Araw, const ushort* __restrict__ WT,
                     const float* __restrict__ bQ, const float* __restrict__ bK,
                     const float* __restrict__ bV,
                     ushort* __restrict__ Qb, ushort* __restrict__ Kb,
                     ushort* __restrict__ Vt)
{
    __shared__ __align__(16) ushort smem[2 * 128 * 72];   // As | Bs; reused as ctile
    ushort* As = smem;
    ushort* Bs = smem + 128 * 72;
    const int tid = threadIdx.x;
    const int m0  = blockIdx.y * 128;
    const int n0g = blockIdx.x * 128;          // 0..6143
    const int sel = n0g >> 11;                 // 0=Q 1=K 2=V
    const int n0  = n0g & 2047;
    const ushort* BT  = WT + (size_t)sel * WELEMS;
    const float* bias = (sel == 0) ? bQ : (sel == 1) ? bK : bV;
    const int w  = tid >> 6;
    const int l  = tid & 63;
    const int wy = w >> 1, wx = w & 1;
    const int q  = l >> 4, lm = l & 15;

    f32x4 acc[4][4];
    #pragma unroll
    for (int i = 0; i < 4; ++i)
        #pragma unroll
        for (int j = 0; j < 4; ++j) acc[i][j] = (f32x4)0.0f;

    uint4  aN[4], bN[4];       // next-tile staging (bf16 A path)
    float4 aN0[4], aN1[4];     // next-tile staging (fp32 A path)

    // ---- prologue: load tile kt=0 into registers ----
    #pragma unroll
    for (int it = 0; it < 4; ++it) {
        const int v = tid + it * 256;
        const int r = v >> 3;
        const int c = (v & 7) << 3;
        if (ABF16) {
            aN[it] = *reinterpret_cast<const uint4*>(
                (const ushort*)Araw + (size_t)(m0 + r) * HIDn + c);
        } else {
            const float* Af = (const float*)Araw + (size_t)(m0 + r) * HIDn + c;
            aN0[it] = *reinterpret_cast<const float4*>(Af);
            aN1[it] = *reinterpret_cast<const float4*>(Af + 4);
        }
        bN[it] = *reinterpret_cast<const uint4*>(BT + (size_t)(n0 + r) * HIDn + c);
    }

    for (int kt = 0; kt < HIDn; kt += 64) {
        // ---- write staged regs -> LDS ----
        #pragma unroll
        for (int it = 0; it < 4; ++it) {
            const int v = tid + it * 256;
            const int r = v >> 3;
            const int c = (v & 7) << 3;
            if (ABF16) {
                *reinterpret_cast<uint4*>(&As[r * 72 + c]) = aN[it];
            } else {
                ushort* d = &As[r * 72 + c];
                d[0] = f2bf(aN0[it].x); d[1] = f2bf(aN0[it].y);
                d[2] = f2bf(aN0[it].z); d[3] = f2bf(aN0[it].w);
                d[4] = f2bf(aN1[it].x); d[5] = f2bf(aN1[it].y);
                d[6] = f2bf(aN1[it].z); d[7] = f2bf(aN1[it].w);
            }
            *reinterpret_cast<uint4*>(&Bs[r * 72 + c]) = bN[it];
        }
        __syncthreads();
        // ---- issue next tile's global loads (latency hidden by compute) ----
        const int kn = kt + 64;
        if (kn < HIDn) {
            #pragma unroll
            for (int it = 0; it < 4; ++it) {
                const int v = tid + it * 256;
                const int r = v >> 3;
                const int c = (v & 7) << 3;
                if (ABF16) {
                    aN[it] = *reinterpret_cast<const uint4*>(
                        (const ushort*)Araw + (size_t)(m0 + r) * HIDn + kn + c);
                } else {
                    const float* Af = (const float*)Araw + (size_t)(m0 + r) * HIDn + kn + c;
                    aN0[it] = *reinterpret_cast<const float4*>(Af);
                    aN1[it] = *reinterpret_cast<const float4*>(Af + 4);
                }
                bN[it] = *reinterpret_cast<const uint4*>(BT + (size_t)(n0 + r) * HIDn + kn + c);
            }
        }
        // ---- compute on tile kt ----
        #pragma unroll
        for (int ks = 0; ks < 2; ++ks) {
            s16x8 af[4], bfv[4];
            #pragma unroll
            for (int im = 0; im < 4; ++im)
                af[im] = *reinterpret_cast<const s16x8*>(&As[(wy * 64 + im * 16 + lm) * 72 + ks * 32 + q * 8]);
            #pragma unroll
            for (int in = 0; in < 4; ++in)
                bfv[in] = *reinterpret_cast<const s16x8*>(&Bs[(wx * 64 + in * 16 + lm) * 72 + ks * 32 + q * 8]);
            #pragma unroll
            for (int im = 0; im < 4; ++im)
                #pragma unroll
                for (int in = 0; in < 4; ++in)
                    acc[im][in] = __builtin_amdgcn_mfma_f32_16x16x32_bf16(af[im], bfv[in], acc[im][in], 0, 0, 0);
        }
        __syncthreads();
    }

    if (sel == 2) {
        // ---- V epilogue: scatter to Vt[b][h][d][s] ----
        #pragma unroll
        for (int in = 0; in < 4; ++in) {
            const int gcol = n0 + wx * 64 + in * 16 + lm;
            const float bv = bias[gcol];
            #pragma unroll
            for (int im = 0; im < 4; ++im) {
                const int grow0 = m0 + wy * 64 + im * 16 + q * 4;
                #pragma unroll
                for (int r = 0; r < 4; ++r) {
                    const float val = acc[im][in][r] + bv;
                    const int grow = grow0 + r;
                    const int bb = grow >> 11, s = grow & (SEQn - 1);
                    const int hh = gcol >> 7,  d = gcol & (HDn - 1);
                    Vt[(((size_t)(bb * NHn + hh)) * HDn + d) * SEQn + s] = f2bf(val);
                }
            }
        }
    } else {
        // ---- Q/K epilogue: C-tile -> LDS (bf16) -> RoPE -> coalesced write --
        ushort* ctile = smem;                  // 128 rows x stride 136 (<= 18432)
        #pragma unroll
        for (int in = 0; in < 4; ++in) {
            const int col = wx * 64 + in * 16 + lm;
            const float bv = bias[n0 + col];
            #pragma unroll
            for (int im = 0; im < 4; ++im) {
                const int row0 = wy * 64 + im * 16 + q * 4;
                #pragma unroll
                for (int r = 0; r < 4; ++r)
                    ctile[(row0 + r) * 136 + col] = f2bf(acc[im][in][r] + bv);
            }
        }
        __syncthreads();
        ushort* dst = (sel == 0) ? Qb : Kb;
        const int d = tid & 63;                // invariant per thread
        const float invf = powf(10000.0f, -(float)d * (1.0f / 64.0f));
        for (int r = tid >> 6; r < 128; r += 4) {
            const int s = (m0 + r) & (SEQn - 1);
            const float ang = (float)s * invf;
            const float cs = cosf(ang), sn = sinf(ang);
            const float t1 = bf2f(ctile[r * 136 + d]);
            const float t2 = bf2f(ctile[r * 136 + 64 + d]);
            const size_t base = (size_t)(m0 + r) * DMn + n0 + d;
            dst[base]      = f2bf(t1 * cs - t2 * sn);
            dst[base + 64] = f2bf(t1 * sn + t2 * cs);
        }
    }
}

// ---- final GEMM: out(4096x2048 fp32) = AO(bf16) * WT^T + bias (fp32) -------
// Same software-pipelined K-loop as gemm_qkv.
__global__ __launch_bounds__(256)
void gemm_out_kernel(const ushort* __restrict__ A, const ushort* __restrict__ BT,
                     const float* __restrict__ bias, float* __restrict__ C)
{
    __shared__ __align__(16) ushort As[128 * 72];
    __shared__ __align__(16) ushort Bs[128 * 72];
    const int tid = threadIdx.x;
    const int m0 = blockIdx.y * 128;
    const int n0 = blockIdx.x * 128;
    const int w  = tid >> 6;
    const int l  = tid & 63;
    const int wy = w >> 1, wx = w & 1;
    const int q  = l >> 4, lm = l & 15;

    f32x4 acc[4][4];
    #pragma unroll
    for (int i = 0; i < 4; ++i)
        #pragma unroll
        for (int j = 0; j < 4; ++j) acc[i][j] = (f32x4)0.0f;

    uint4 aN[4], bN[4];
    #pragma unroll
    for (int it = 0; it < 4; ++it) {
        const int v = tid + it * 256;
        const int r = v >> 3;
        const int c = (v & 7) << 3;
        aN[it] = *reinterpret_cast<const uint4*>(A  + (size_t)(m0 + r) * DMn + c);
        bN[it] = *reinterpret_cast<const uint4*>(BT + (size_t)(n0 + r) * DMn + c);
    }

    for (int kt = 0; kt < DMn; kt += 64) {
        #pragma unroll
        for (int it = 0; it < 4; ++it) {
            const int v = tid + it * 256;
            const int r = v >> 3;
            const int c = (v & 7) << 3;
            *reinterpret_cast<uint4*>(&As[r * 72 + c]) = aN[it];
            *reinterpret_cast<uint4*>(&Bs[r * 72 + c]) = bN[it];
        }
        __syncthreads();
        const int kn = kt + 64;
        if (kn < DMn) {
            #pragma unroll
            for (int it = 0; it < 4; ++it) {
                const int v = tid + it * 256;
                const int r = v >> 3;
                const int c = (v & 7) << 3;
                aN[it] = *reinterpret_cast<const uint4*>(A  + (size_t)(m0 + r) * DMn + kn + c);
                bN[it] = *reinterpret_cast<const uint4*>(BT + (size_t)(n0 + r) * DMn + kn + c);
            }
        }
        #pragma unroll
        for (int ks = 0; ks < 2; ++ks) {
            s16x8 af[4], bfv[4];
            #pragma unroll
            for (int im = 0; im < 4; ++im)
                af[im] = *reinterpret_cast<const s16x8*>(&As[(wy * 64 + im * 16 + lm) * 72 + ks * 32 + q * 8]);
            #pragma unroll
            for (int in = 0; in < 4; ++in)
                bfv[in] = *reinterpret_cast<const s16x8*>(&Bs[(wx * 64 + in * 16 + lm) * 72 + ks * 32 + q * 8]);
            #pragma unroll
            for (int im = 0; im < 4; ++im)
                #pragma unroll
                for (int in = 0; in < 4; ++in)
                    acc[im][in] = __builtin_amdgcn_mfma_f32_16x16x32_bf16(af[im], bfv[in], acc[im][in], 0, 0, 0);
        }
        __syncthreads();
    }
    #pragma unroll
    for (int in = 0; in < 4; ++in) {
        const int gcol = n0 + wx * 64 + in * 16 + lm;
        const float bv = bias[gcol];
        #pragma unroll
        for (int im = 0; im < 4; ++im) {
            const int grow0 = m0 + wy * 64 + im * 16 + q * 4;
            #pragma unroll
            for (int r = 0; r < 4; ++r)
                C[(size_t)(grow0 + r) * HIDn + gcol] = acc[im][in][r] + bv;
        }
    }
}

// -------- MFMA flash attention (round-4 version, measured 90 us) ------------
// 4 waves/block, one (b,h,16-query tile) per wave. Q/K bf16 [b][s][h][d];
// Vt bf16 [b][h][d][s]; AO aliases Q in-place (1:1 wave<->rows mapping).
__global__ __launch_bounds__(256)
void attn_mfma_kernel(const ushort* Q, const ushort* __restrict__ K,
                      const ushort* __restrict__ Vt, const float* __restrict__ kw,
                      ushort* AO)
{
    __shared__ ushort plds[4][16 * 40];   // per-wave P tile, stride 40 (2-way = free)
    const int w  = threadIdx.x >> 6;
    const int l  = threadIdx.x & 63;
    const int q  = l >> 4, lm = l & 15;
    const int gw = blockIdx.x * 4 + w;     // b(1) | h(4) | qt(7)
    const int qt = gw & 127;
    const int h  = (gw >> 7) & (NHn - 1);
    const int b  = gw >> 11;
    const int q0 = qt * 16;
    const float f = kw[h] * 0.08838834764831845f;   // kw * HD^-0.5

    s16x8 qf[4];
    const size_t qbase = ((size_t)(b * SEQn + q0 + lm)) * DMn + h * HDn;
    #pragma unroll
    for (int ks = 0; ks < 4; ++ks)
        qf[ks] = *reinterpret_cast<const s16x8*>(Q + qbase + ks * 32 + q * 8);

    f32x4 O[8];
    #pragma unroll
    for (int nt = 0; nt < 8; ++nt) O[nt] = (f32x4)0.0f;
    float m[4]    = {-1e30f, -1e30f, -1e30f, -1e30f};
    float lsum[4] = {0.f, 0.f, 0.f, 0.f};

    const int lo = q0 - WINn;
    const int c0 = lo > 0 ? (lo & ~31) : 0;
    const int nch = (q0 + 16 - c0 + 31) >> 5;

    const size_t kbh = ((size_t)(b * SEQn)) * DMn + h * HDn;
    const size_t vbh = ((size_t)(b * NHn + h)) * HDn * SEQn;

    for (int c = 0; c < nch; ++c) {
        const int kc = c0 + c * 32;
        f32x4 S[2];
        #pragma unroll
        for (int t = 0; t < 2; ++t) {
            f32x4 acc = (f32x4)0.0f;
            const size_t krow = kbh + (size_t)(kc + t * 16 + lm) * DMn;
            #pragma unroll
            for (int ks = 0; ks < 4; ++ks) {
                const s16x8 kf = *reinterpret_cast<const s16x8*>(K + krow + ks * 32 + q * 8);
                acc = __builtin_amdgcn_mfma_f32_16x16x32_bf16(qf[ks], kf, acc, 0, 0, 0);
            }
            S[t] = acc;
        }
        const int j0 = kc + lm, j1 = kc + 16 + lm;
        #pragma unroll
        for (int r = 0; r < 4; ++r) {
            const int i = q0 + q * 4 + r;
            float v0 = S[0][r] * f;
            float v1 = S[1][r] * f;
            if (j0 > i || j0 < i - WINn) v0 = -1e30f;
            if (j1 > i || j1 < i - WINn) v1 = -1e30f;
            float mx = fmaxf(v0, v1);
            #pragma unroll
            for (int off = 8; off > 0; off >>= 1)
                mx = fmaxf(mx, __shfl_xor(mx, off));
            const float mn = fmaxf(m[r], mx);
            const float alpha = __expf(m[r] - mn);
            m[r] = mn;
            const ushort h0 = f2bf(__expf(v0 - mn));
            const ushort h1 = f2bf(__expf(v1 - mn));
            plds[w][(q * 4 + r) * 40 + lm]      = h0;
            plds[w][(q * 4 + r) * 40 + 16 + lm] = h1;
            float ps = bf2f(h0) + bf2f(h1);
            #pragma unroll
            for (int off = 8; off > 0; off >>= 1)
                ps += __shfl_xor(ps, off);
            lsum[r] = lsum[r] * alpha + ps;
            #pragma unroll
            for (int nt = 0; nt < 8; ++nt) O[nt][r] *= alpha;
        }
        const s16x8 pf = *reinterpret_cast<const s16x8*>(&plds[w][lm * 40 + q * 8]);
        #pragma unroll
        for (int nt = 0; nt < 8; ++nt) {
            const s16x8 vf = *reinterpret_cast<const s16x8*>(
                Vt + vbh + (size_t)(nt * 16 + lm) * SEQn + kc + q * 8);
            O[nt] = __builtin_amdgcn_mfma_f32_16x16x32_bf16(pf, vf, O[nt], 0, 0, 0);
        }
    }
    #pragma unroll
    for (int r = 0; r < 4; ++r) {
        const float inv = 1.0f / lsum[r];
        const size_t orow = ((size_t)(b * SEQn + q0 + q * 4 + r)) * DMn + h * HDn;
        #pragma unroll
        for (int nt = 0; nt < 8; ++nt)
            AO[orow + nt * 16 + lm] = f2bf(O[nt][r] * inv);
    }
}

extern "C" void kernel_launch(void* const* d_in, const int* in_sizes, int n_in,
                              void* d_out, int out_size, void* d_ws, size_t ws_size,
                              hipStream_t stream)
{
    (void)in_sizes; (void)n_in; (void)out_size;
    const float* x  = (const float*)d_in[0];
    const float* WQ = (const float*)d_in[1];
    const float* bQ = (const float*)d_in[2];
    const float* WK = (const float*)d_in[3];
    const float* bK = (const float*)d_in[4];
    const float* WV = (const float*)d_in[5];
    const float* bV = (const float*)d_in[6];
    const float* WO = (const float*)d_in[7];
    const float* bO = (const float*)d_in[8];
    const float* kw = (const float*)d_in[9];
    float* out = (float*)d_out;

    // Workspace: Qb/Kb/Vt bf16 (16 MB each) + WT 3 slabs (24 MB) = 72 MB;
    // + optional xb (16 MB) = 88 MB when ws_size permits.
    char* ws = (char*)d_ws;
    const size_t AELEMS = (size_t)MROWS * DMn;         // 4096*2048
    ushort* Qb = (ushort*)ws;                          // also AO (in-place)
    ushort* Kb = (ushort*)(ws + AELEMS * 2);
    ushort* Vt = (ushort*)(ws + AELEMS * 4);           // [b][h][d][s]
    ushort* WT = (ushort*)(ws + AELEMS * 6);           // 3 x 2048x2048 bf16
    ushort* xb = (ushort*)(ws + AELEMS * 6 + WELEMS * 6);
    const bool have_xb = ws_size >= (size_t)(AELEMS * 6 + WELEMS * 6) + AELEMS * 2;

    const dim3 tblk(32, 8);

    transpose_qkv_kernel<<<dim3(64, 64, 3), tblk, 0, stream>>>(WQ, WK, WV, WT);

    if (have_xb) {
        cvt_kernel<<<(int)(AELEMS / 1024), 256, 0, stream>>>(x, xb);
        gemm_qkv_kernel<1><<<dim3(3 * DMn / 128, MROWS / 128), 256, 0, stream>>>(
            xb, WT, bQ, bK, bV, Qb, Kb, Vt);
    } else {
        gemm_qkv_kernel<0><<<dim3(3 * DMn / 128, MROWS / 128), 256, 0, stream>>>(
            x, WT, bQ, bK, bV, Qb, Kb, Vt);
    }

    attn_mfma_kernel<<<dim3(BATCHn * NHn * (SEQn / 16) / 4), 256, 0, stream>>>(Qb, Kb, Vt, kw, Qb);

    transpose_cvt_kernel<<<dim3(64, 64), tblk, 0, stream>>>(WO, WT);
    gemm_out_kernel<<<dim3(HIDn / 128, MROWS / 128), 256, 0, stream>>>(Qb, WT, bO, out);
}

// Round 9
// 433.099 us; speedup vs baseline: 1.9222x; 1.9222x over previous
//
#include <hip/hip_runtime.h>
#include <cstdint>

#define SEQn   2048
#define NHn    16
#define HDn    128
#define DMn    2048   // NH*HD
#define HIDn   2048
#define BATCHn 2
#define WINn   256
#define MROWS  (BATCHn*SEQn)  // 4096
#define WELEMS ((size_t)HIDn * DMn)

typedef short s16x8 __attribute__((ext_vector_type(8)));  // 8 bf16 (4 VGPRs)
typedef float f32x4 __attribute__((ext_vector_type(4)));  // MFMA accumulator

__device__ __forceinline__ float bf2f(ushort x) {
    union { uint u; float f; } v; v.u = ((uint)x) << 16; return v.f;
}
__device__ __forceinline__ ushort f2bf(float f) {
    union { float f; uint u; } v; v.f = f;
    uint u = v.u;
    return (ushort)((u + 0x7FFFu + ((u >> 16) & 1u)) >> 16);  // RNE
}

// ---------------- x fp32 -> bf16 convert (coalesced, float4 in / ushort4 out)
__global__ __launch_bounds__(256)
void cvt_kernel(const float* __restrict__ src, ushort* __restrict__ dst)
{
    const int i = (blockIdx.x * 256 + threadIdx.x) * 4;
    const float4 v = *reinterpret_cast<const float4*>(src + i);
    ushort4 o;
    o.x = f2bf(v.x); o.y = f2bf(v.y); o.z = f2bf(v.z); o.w = f2bf(v.w);
    *reinterpret_cast<ushort4*>(dst + i) = o;
}

// --- batched transpose+convert: {WQ,WK,WV}[k][n] fp32 -> WT[z][n][k] bf16 ----
__global__ __launch_bounds__(256)
void transpose_qkv_kernel(const float* __restrict__ WQ, const float* __restrict__ WK,
                          const float* __restrict__ WV, ushort* __restrict__ WT)
{
    __shared__ ushort t[32][33];
    const float* src = (blockIdx.z == 0) ? WQ : (blockIdx.z == 1) ? WK : WV;
    ushort* dst = WT + (size_t)blockIdx.z * WELEMS;
    const int tx = threadIdx.x, ty = threadIdx.y;
    const int n  = blockIdx.x * 32 + tx;
    const int k0 = blockIdx.y * 32;
    #pragma unroll
    for (int r = ty; r < 32; r += 8)
        t[r][tx] = f2bf(src[(size_t)(k0 + r) * 2048 + n]);
    __syncthreads();
    const int k  = k0 + tx;
    const int nb = blockIdx.x * 32;
    #pragma unroll
    for (int r = ty; r < 32; r += 8)
        dst[(size_t)(nb + r) * 2048 + k] = t[tx][r];
}

// ------- single transpose+convert: W[k][n] fp32 -> WT[n][k] bf16 -------------
__global__ __launch_bounds__(256)
void transpose_cvt_kernel(const float* __restrict__ src, ushort* __restrict__ dst)
{
    __shared__ ushort t[32][33];
    const int tx = threadIdx.x, ty = threadIdx.y;
    const int n  = blockIdx.x * 32 + tx;
    const int k0 = blockIdx.y * 32;
    #pragma unroll
    for (int r = ty; r < 32; r += 8)
        t[r][tx] = f2bf(src[(size_t)(k0 + r) * 2048 + n]);
    __syncthreads();
    const int k  = k0 + tx;
    const int nb = blockIdx.x * 32;
    #pragma unroll
    for (int r = ty; r < 32; r += 8)
        dst[(size_t)(nb + r) * 2048 + k] = t[tx][r];
}

// -------- fused QKV GEMM + fused RoPE epilogue ------------------------------
// [Q|K|V](4096x6144) = x(4096x2048) * WT^T + bias.
// K-loop is the round-7 measured structure (NO loop-carried staging regs —
// the r8 software pipeline spilled 1.1 GB of scratch).
// Each block covers exactly ONE head (128 cols), so RoPE pairs (d, d+64) are
// intra-block: Q/K epilogue routes the C-tile through reused LDS, applies
// RoPE, writes coalesced. V epilogue scatters to Vt[b][h][d][s].
// C/D: col=lane&15, row=(lane>>4)*4+reg  (m89-verified mapping).
template<int ABF16>
__global__ __launch_bounds__(256)
void gemm_qkv_kernel(const void* __restrict__ Araw, const ushort* __restrict__ WT,
                     const float* __restrict__ bQ, const float* __restrict__ bK,
                     const float* __restrict__ bV,
                     ushort* __restrict__ Qb, ushort* __restrict__ Kb,
                     ushort* __restrict__ Vt)
{
    __shared__ __align__(16) ushort smem[2 * 128 * 72];   // As | Bs; reused as ctile
    ushort* As = smem;
    ushort* Bs = smem + 128 * 72;
    const int tid = threadIdx.x;
    const int m0  = blockIdx.y * 128;
    const int n0g = blockIdx.x * 128;          // 0..6143
    const int sel = n0g >> 11;                 // 0=Q 1=K 2=V
    const int n0  = n0g & 2047;
    const ushort* BT  = WT + (size_t)sel * WELEMS;
    const float* bias = (sel == 0) ? bQ : (sel == 1) ? bK : bV;
    const int w  = tid >> 6;
    const int l  = tid & 63;
    const int wy = w >> 1, wx = w & 1;
    const int q  = l >> 4, lm = l & 15;

    f32x4 acc[4][4];
    #pragma unroll
    for (int i = 0; i < 4; ++i)
        #pragma unroll
        for (int j = 0; j < 4; ++j) acc[i][j] = (f32x4)0.0f;

    for (int kt = 0; kt < HIDn; kt += 64) {
        #pragma unroll
        for (int it = 0; it < 4; ++it) {
            const int v = tid + it * 256;
            const int r = v >> 3;
            const int c = (v & 7) << 3;
            if (ABF16) {
                const uint4 av = *reinterpret_cast<const uint4*>(
                    (const ushort*)Araw + (size_t)(m0 + r) * HIDn + kt + c);
                *reinterpret_cast<uint4*>(&As[r * 72 + c]) = av;
            } else {
                const float* Af = (const float*)Araw + (size_t)(m0 + r) * HIDn + kt + c;
                const float4 a0 = *reinterpret_cast<const float4*>(Af);
                const float4 a1 = *reinterpret_cast<const float4*>(Af + 4);
                ushort* d = &As[r * 72 + c];
                d[0] = f2bf(a0.x); d[1] = f2bf(a0.y); d[2] = f2bf(a0.z); d[3] = f2bf(a0.w);
                d[4] = f2bf(a1.x); d[5] = f2bf(a1.y); d[6] = f2bf(a1.z); d[7] = f2bf(a1.w);
            }
            const uint4 bv = *reinterpret_cast<const uint4*>(BT + (size_t)(n0 + r) * HIDn + kt + c);
            *reinterpret_cast<uint4*>(&Bs[r * 72 + c]) = bv;
        }
        __syncthreads();
        #pragma unroll
        for (int ks = 0; ks < 2; ++ks) {
            s16x8 af[4], bfv[4];
            #pragma unroll
            for (int im = 0; im < 4; ++im)
                af[im] = *reinterpret_cast<const s16x8*>(&As[(wy * 64 + im * 16 + lm) * 72 + ks * 32 + q * 8]);
            #pragma unroll
            for (int in = 0; in < 4; ++in)
                bfv[in] = *reinterpret_cast<const s16x8*>(&Bs[(wx * 64 + in * 16 + lm) * 72 + ks * 32 + q * 8]);
            #pragma unroll
            for (int im = 0; im < 4; ++im)
                #pragma unroll
                for (int in = 0; in < 4; ++in)
                    acc[im][in] = __builtin_amdgcn_mfma_f32_16x16x32_bf16(af[im], bfv[in], acc[im][in], 0, 0, 0);
        }
        __syncthreads();
    }

    if (sel == 2) {
        // ---- V epilogue: scatter to Vt[b][h][d][s] ----
        #pragma unroll
        for (int in = 0; in < 4; ++in) {
            const int gcol = n0 + wx * 64 + in * 16 + lm;
            const float bv = bias[gcol];
            #pragma unroll
            for (int im = 0; im < 4; ++im) {
                const int grow0 = m0 + wy * 64 + im * 16 + q * 4;
                #pragma unroll
                for (int r = 0; r < 4; ++r) {
                    const float val = acc[im][in][r] + bv;
                    const int grow = grow0 + r;
                    const int bb = grow >> 11, s = grow & (SEQn - 1);
                    const int hh = gcol >> 7,  d = gcol & (HDn - 1);
                    Vt[(((size_t)(bb * NHn + hh)) * HDn + d) * SEQn + s] = f2bf(val);
                }
            }
        }
    } else {
        // ---- Q/K epilogue: C-tile -> LDS (bf16) -> RoPE -> coalesced write --
        ushort* ctile = smem;                  // 128 rows x stride 136 (fits 36864 B)
        #pragma unroll
        for (int in = 0; in < 4; ++in) {
            const int col = wx * 64 + in * 16 + lm;
            const float bv = bias[n0 + col];
            #pragma unroll
            for (int im = 0; im < 4; ++im) {
                const int row0 = wy * 64 + im * 16 + q * 4;
                #pragma unroll
                for (int r = 0; r < 4; ++r)
                    ctile[(row0 + r) * 136 + col] = f2bf(acc[im][in][r] + bv);
            }
        }
        __syncthreads();
        ushort* dst = (sel == 0) ? Qb : Kb;
        const int d = tid & 63;                // invariant per thread
        const float invf = powf(10000.0f, -(float)d * (1.0f / 64.0f));
        for (int r = tid >> 6; r < 128; r += 4) {
            const int s = (m0 + r) & (SEQn - 1);
            const float ang = (float)s * invf;
            const float cs = cosf(ang), sn = sinf(ang);
            const float t1 = bf2f(ctile[r * 136 + d]);
            const float t2 = bf2f(ctile[r * 136 + 64 + d]);
            const size_t base = (size_t)(m0 + r) * DMn + n0 + d;
            dst[base]      = f2bf(t1 * cs - t2 * sn);
            dst[base + 64] = f2bf(t1 * sn + t2 * cs);
        }
    }
}

// ---- final GEMM: out(4096x2048 fp32) = AO(bf16) * WT^T + bias (fp32) -------
// Round-7 measured structure (non-pipelined).
__global__ __launch_bounds__(256)
void gemm_out_kernel(const ushort* __restrict__ A, const ushort* __restrict__ BT,
                     const float* __restrict__ bias, float* __restrict__ C)
{
    __shared__ __align__(16) ushort As[128 * 72];
    __shared__ __align__(16) ushort Bs[128 * 72];
    const int tid = threadIdx.x;
    const int m0 = blockIdx.y * 128;
    const int n0 = blockIdx.x * 128;
    const int w  = tid >> 6;
    const int l  = tid & 63;
    const int wy = w >> 1, wx = w & 1;
    const int q  = l >> 4, lm = l & 15;

    f32x4 acc[4][4];
    #pragma unroll
    for (int i = 0; i < 4; ++i)
        #pragma unroll
        for (int j = 0; j < 4; ++j) acc[i][j] = (f32x4)0.0f;

    for (int kt = 0; kt < DMn; kt += 64) {
        #pragma unroll
        for (int it = 0; it < 4; ++it) {
            const int v = tid + it * 256;
            const int r = v >> 3;
            const int c = (v & 7) << 3;
            const uint4 av = *reinterpret_cast<const uint4*>(A + (size_t)(m0 + r) * DMn + kt + c);
            *reinterpret_cast<uint4*>(&As[r * 72 + c]) = av;
            const uint4 bv = *reinterpret_cast<const uint4*>(BT + (size_t)(n0 + r) * DMn + kt + c);
            *reinterpret_cast<uint4*>(&Bs[r * 72 + c]) = bv;
        }
        __syncthreads();
        #pragma unroll
        for (int ks = 0; ks < 2; ++ks) {
            s16x8 af[4], bfv[4];
            #pragma unroll
            for (int im = 0; im < 4; ++im)
                af[im] = *reinterpret_cast<const s16x8*>(&As[(wy * 64 + im * 16 + lm) * 72 + ks * 32 + q * 8]);
            #pragma unroll
            for (int in = 0; in < 4; ++in)
                bfv[in] = *reinterpret_cast<const s16x8*>(&Bs[(wx * 64 + in * 16 + lm) * 72 + ks * 32 + q * 8]);
            #pragma unroll
            for (int im = 0; im < 4; ++im)
                #pragma unroll
                for (int in = 0; in < 4; ++in)
                    acc[im][in] = __builtin_amdgcn_mfma_f32_16x16x32_bf16(af[im], bfv[in], acc[im][in], 0, 0, 0);
        }
        __syncthreads();
    }
    #pragma unroll
    for (int in = 0; in < 4; ++in) {
        const int gcol = n0 + wx * 64 + in * 16 + lm;
        const float bv = bias[gcol];
        #pragma unroll
        for (int im = 0; im < 4; ++im) {
            const int grow0 = m0 + wy * 64 + im * 16 + q * 4;
            #pragma unroll
            for (int r = 0; r < 4; ++r)
                C[(size_t)(grow0 + r) * HIDn + gcol] = acc[im][in][r] + bv;
        }
    }
}

// -------- MFMA flash attention (round-4 version, measured 90 us) ------------
// 4 waves/block, one (b,h,16-query tile) per wave. Q/K bf16 [b][s][h][d];
// Vt bf16 [b][h][d][s]; AO aliases Q in-place (1:1 wave<->rows mapping).
__global__ __launch_bounds__(256)
void attn_mfma_kernel(const ushort* Q, const ushort* __restrict__ K,
                      const ushort* __restrict__ Vt, const float* __restrict__ kw,
                      ushort* AO)
{
    __shared__ ushort plds[4][16 * 40];   // per-wave P tile, stride 40 (2-way = free)
    const int w  = threadIdx.x >> 6;
    const int l  = threadIdx.x & 63;
    const int q  = l >> 4, lm = l & 15;
    const int gw = blockIdx.x * 4 + w;     // b(1) | h(4) | qt(7)
    const int qt = gw & 127;
    const int h  = (gw >> 7) & (NHn - 1);
    const int b  = gw >> 11;
    const int q0 = qt * 16;
    const float f = kw[h] * 0.08838834764831845f;   // kw * HD^-0.5

    s16x8 qf[4];
    const size_t qbase = ((size_t)(b * SEQn + q0 + lm)) * DMn + h * HDn;
    #pragma unroll
    for (int ks = 0; ks < 4; ++ks)
        qf[ks] = *reinterpret_cast<const s16x8*>(Q + qbase + ks * 32 + q * 8);

    f32x4 O[8];
    #pragma unroll
    for (int nt = 0; nt < 8; ++nt) O[nt] = (f32x4)0.0f;
    float m[4]    = {-1e30f, -1e30f, -1e30f, -1e30f};
    float lsum[4] = {0.f, 0.f, 0.f, 0.f};

    const int lo = q0 - WINn;
    const int c0 = lo > 0 ? (lo & ~31) : 0;
    const int nch = (q0 + 16 - c0 + 31) >> 5;

    const size_t kbh = ((size_t)(b * SEQn)) * DMn + h * HDn;
    const size_t vbh = ((size_t)(b * NHn + h)) * HDn * SEQn;

    for (int c = 0; c < nch; ++c) {
        const int kc = c0 + c * 32;
        f32x4 S[2];
        #pragma unroll
        for (int t = 0; t < 2; ++t) {
            f32x4 acc = (f32x4)0.0f;
            const size_t krow = kbh + (size_t)(kc + t * 16 + lm) * DMn;
            #pragma unroll
            for (int ks = 0; ks < 4; ++ks) {
                const s16x8 kf = *reinterpret_cast<const s16x8*>(K + krow + ks * 32 + q * 8);
                acc = __builtin_amdgcn_mfma_f32_16x16x32_bf16(qf[ks], kf, acc, 0, 0, 0);
            }
            S[t] = acc;
        }
        const int j0 = kc + lm, j1 = kc + 16 + lm;
        #pragma unroll
        for (int r = 0; r < 4; ++r) {
            const int i = q0 + q * 4 + r;
            float v0 = S[0][r] * f;
            float v1 = S[1][r] * f;
            if (j0 > i || j0 < i - WINn) v0 = -1e30f;
            if (j1 > i || j1 < i - WINn) v1 = -1e30f;
            float mx = fmaxf(v0, v1);
            #pragma unroll
            for (int off = 8; off > 0; off >>= 1)
                mx = fmaxf(mx, __shfl_xor(mx, off));
            const float mn = fmaxf(m[r], mx);
            const float alpha = __expf(m[r] - mn);
            m[r] = mn;
            const ushort h0 = f2bf(__expf(v0 - mn));
            const ushort h1 = f2bf(__expf(v1 - mn));
            plds[w][(q * 4 + r) * 40 + lm]      = h0;
            plds[w][(q * 4 + r) * 40 + 16 + lm] = h1;
            float ps = bf2f(h0) + bf2f(h1);
            #pragma unroll
            for (int off = 8; off > 0; off >>= 1)
                ps += __shfl_xor(ps, off);
            lsum[r] = lsum[r] * alpha + ps;
            #pragma unroll
            for (int nt = 0; nt < 8; ++nt) O[nt][r] *= alpha;
        }
        const s16x8 pf = *reinterpret_cast<const s16x8*>(&plds[w][lm * 40 + q * 8]);
        #pragma unroll
        for (int nt = 0; nt < 8; ++nt) {
            const s16x8 vf = *reinterpret_cast<const s16x8*>(
                Vt + vbh + (size_t)(nt * 16 + lm) * SEQn + kc + q * 8);
            O[nt] = __builtin_amdgcn_mfma_f32_16x16x32_bf16(pf, vf, O[nt], 0, 0, 0);
        }
    }
    #pragma unroll
    for (int r = 0; r < 4; ++r) {
        const float inv = 1.0f / lsum[r];
        const size_t orow = ((size_t)(b * SEQn + q0 + q * 4 + r)) * DMn + h * HDn;
        #pragma unroll
        for (int nt = 0; nt < 8; ++nt)
            AO[orow + nt * 16 + lm] = f2bf(O[nt][r] * inv);
    }
}

extern "C" void kernel_launch(void* const* d_in, const int* in_sizes, int n_in,
                              void* d_out, int out_size, void* d_ws, size_t ws_size,
                              hipStream_t stream)
{
    (void)in_sizes; (void)n_in; (void)out_size;
    const float* x  = (const float*)d_in[0];
    const float* WQ = (const float*)d_in[1];
    const float* bQ = (const float*)d_in[2];
    const float* WK = (const float*)d_in[3];
    const float* bK = (const float*)d_in[4];
    const float* WV = (const float*)d_in[5];
    const float* bV = (const float*)d_in[6];
    const float* WO = (const float*)d_in[7];
    const float* bO = (const float*)d_in[8];
    const float* kw = (const float*)d_in[9];
    float* out = (float*)d_out;

    // Workspace: Qb/Kb/Vt bf16 (16 MB each) + WT 3 slabs (24 MB) = 72 MB;
    // + optional xb (16 MB) = 88 MB when ws_size permits.
    char* ws = (char*)d_ws;
    const size_t AELEMS = (size_t)MROWS * DMn;         // 4096*2048
    ushort* Qb = (ushort*)ws;                          // also AO (in-place)
    ushort* Kb = (ushort*)(ws + AELEMS * 2);
    ushort* Vt = (ushort*)(ws + AELEMS * 4);           // [b][h][d][s]
    ushort* WT = (ushort*)(ws + AELEMS * 6);           // 3 x 2048x2048 bf16
    ushort* xb = (ushort*)(ws + AELEMS * 6 + WELEMS * 6);
    const bool have_xb = ws_size >= (size_t)(AELEMS * 6 + WELEMS * 6) + AELEMS * 2;

    const dim3 tblk(32, 8);

    transpose_qkv_kernel<<<dim3(64, 64, 3), tblk, 0, stream>>>(WQ, WK, WV, WT);

    if (have_xb) {
        cvt_kernel<<<(int)(AELEMS / 1024), 256, 0, stream>>>(x, xb);
        gemm_qkv_kernel<1><<<dim3(3 * DMn / 128, MROWS / 128), 256, 0, stream>>>(
            xb, WT, bQ, bK, bV, Qb, Kb, Vt);
    } else {
        gemm_qkv_kernel<0><<<dim3(3 * DMn / 128, MROWS / 128), 256, 0, stream>>>(
            x, WT, bQ, bK, bV, Qb, Kb, Vt);
    }

    attn_mfma_kernel<<<dim3(BATCHn * NHn * (SEQn / 16) / 4), 256, 0, stream>>>(Qb, Kb, Vt, kw, Qb);

    transpose_cvt_kernel<<<dim3(64, 64), tblk, 0, stream>>>(WO, WT);
    gemm_out_kernel<<<dim3(HIDn / 128, MROWS / 128), 256, 0, stream>>>(Qb, WT, bO, out);
}

// Round 10
// 431.562 us; speedup vs baseline: 1.9290x; 1.0036x over previous
//
#include <hip/hip_runtime.h>
#include <cstdint>

#define SEQn   2048
#define NHn    16
#define HDn    128
#define DMn    2048   // NH*HD
#define HIDn   2048
#define BATCHn 2
#define WINn   256
#define MROWS  (BATCHn*SEQn)  // 4096
#define WELEMS ((size_t)HIDn * DMn)

typedef short s16x8 __attribute__((ext_vector_type(8)));  // 8 bf16 (4 VGPRs)
typedef float f32x4 __attribute__((ext_vector_type(4)));  // MFMA accumulator

__device__ __forceinline__ float bf2f(ushort x) {
    union { uint u; float f; } v; v.u = ((uint)x) << 16; return v.f;
}
__device__ __forceinline__ ushort f2bf(float f) {
    union { float f; uint u; } v; v.f = f;
    uint u = v.u;
    return (ushort)((u + 0x7FFFu + ((u >> 16) & 1u)) >> 16);  // RNE
}

// --- batched transpose+convert {WQ,WK,WV} -> WT slabs, plus z=3: x -> xb ----
__global__ __launch_bounds__(256)
void transpose_qkv_kernel(const float* __restrict__ WQ, const float* __restrict__ WK,
                          const float* __restrict__ WV, ushort* __restrict__ WT,
                          const float* __restrict__ x, ushort* __restrict__ xb)
{
    const int tid = threadIdx.y * 32 + threadIdx.x;
    if (blockIdx.z == 3) {
        // x fp32 -> bf16: 4096 blocks x 256 threads x 8 elems = 8.4M
        const int bid = blockIdx.y * 64 + blockIdx.x;
        const size_t base = ((size_t)bid * 256 + tid) * 8;
        const float4 a0 = *reinterpret_cast<const float4*>(x + base);
        const float4 a1 = *reinterpret_cast<const float4*>(x + base + 4);
        ushort4 o0, o1;
        o0.x = f2bf(a0.x); o0.y = f2bf(a0.y); o0.z = f2bf(a0.z); o0.w = f2bf(a0.w);
        o1.x = f2bf(a1.x); o1.y = f2bf(a1.y); o1.z = f2bf(a1.z); o1.w = f2bf(a1.w);
        *reinterpret_cast<ushort4*>(xb + base)     = o0;
        *reinterpret_cast<ushort4*>(xb + base + 4) = o1;
        return;
    }
    __shared__ ushort t[32][33];
    const float* src = (blockIdx.z == 0) ? WQ : (blockIdx.z == 1) ? WK : WV;
    ushort* dst = WT + (size_t)blockIdx.z * WELEMS;
    const int tx = threadIdx.x, ty = threadIdx.y;
    const int n  = blockIdx.x * 32 + tx;
    const int k0 = blockIdx.y * 32;
    #pragma unroll
    for (int r = ty; r < 32; r += 8)
        t[r][tx] = f2bf(src[(size_t)(k0 + r) * 2048 + n]);
    __syncthreads();
    const int k  = k0 + tx;
    const int nb = blockIdx.x * 32;
    #pragma unroll
    for (int r = ty; r < 32; r += 8)
        dst[(size_t)(nb + r) * 2048 + k] = t[tx][r];
}

// ------- single transpose+convert: W[k][n] fp32 -> WT[n][k] bf16 -------------
__global__ __launch_bounds__(256)
void transpose_cvt_kernel(const float* __restrict__ src, ushort* __restrict__ dst)
{
    __shared__ ushort t[32][33];
    const int tx = threadIdx.x, ty = threadIdx.y;
    const int n  = blockIdx.x * 32 + tx;
    const int k0 = blockIdx.y * 32;
    #pragma unroll
    for (int r = ty; r < 32; r += 8)
        t[r][tx] = f2bf(src[(size_t)(k0 + r) * 2048 + n]);
    __syncthreads();
    const int k  = k0 + tx;
    const int nb = blockIdx.x * 32;
    #pragma unroll
    for (int r = ty; r < 32; r += 8)
        dst[(size_t)(nb + r) * 2048 + k] = t[tx][r];
}

// -------- fused QKV GEMM + fused RoPE epilogue (round-9 measured: 172 us) ---
template<int ABF16>
__global__ __launch_bounds__(256)
void gemm_qkv_kernel(const void* __restrict__ Araw, const ushort* __restrict__ WT,
                     const float* __restrict__ bQ, const float* __restrict__ bK,
                     const float* __restrict__ bV,
                     ushort* __restrict__ Qb, ushort* __restrict__ Kb,
                     ushort* __restrict__ Vt)
{
    __shared__ __align__(16) ushort smem[2 * 128 * 72];   // As | Bs; reused as ctile
    ushort* As = smem;
    ushort* Bs = smem + 128 * 72;
    const int tid = threadIdx.x;
    const int m0  = blockIdx.y * 128;
    const int n0g = blockIdx.x * 128;          // 0..6143
    const int sel = n0g >> 11;                 // 0=Q 1=K 2=V
    const int n0  = n0g & 2047;
    const ushort* BT  = WT + (size_t)sel * WELEMS;
    const float* bias = (sel == 0) ? bQ : (sel == 1) ? bK : bV;
    const int w  = tid >> 6;
    const int l  = tid & 63;
    const int wy = w >> 1, wx = w & 1;
    const int q  = l >> 4, lm = l & 15;

    f32x4 acc[4][4];
    #pragma unroll
    for (int i = 0; i < 4; ++i)
        #pragma unroll
        for (int j = 0; j < 4; ++j) acc[i][j] = (f32x4)0.0f;

    for (int kt = 0; kt < HIDn; kt += 64) {
        #pragma unroll
        for (int it = 0; it < 4; ++it) {
            const int v = tid + it * 256;
            const int r = v >> 3;
            const int c = (v & 7) << 3;
            if (ABF16) {
                const uint4 av = *reinterpret_cast<const uint4*>(
                    (const ushort*)Araw + (size_t)(m0 + r) * HIDn + kt + c);
                *reinterpret_cast<uint4*>(&As[r * 72 + c]) = av;
            } else {
                const float* Af = (const float*)Araw + (size_t)(m0 + r) * HIDn + kt + c;
                const float4 a0 = *reinterpret_cast<const float4*>(Af);
                const float4 a1 = *reinterpret_cast<const float4*>(Af + 4);
                ushort* d = &As[r * 72 + c];
                d[0] = f2bf(a0.x); d[1] = f2bf(a0.y); d[2] = f2bf(a0.z); d[3] = f2bf(a0.w);
                d[4] = f2bf(a1.x); d[5] = f2bf(a1.y); d[6] = f2bf(a1.z); d[7] = f2bf(a1.w);
            }
            const uint4 bv = *reinterpret_cast<const uint4*>(BT + (size_t)(n0 + r) * HIDn + kt + c);
            *reinterpret_cast<uint4*>(&Bs[r * 72 + c]) = bv;
        }
        __syncthreads();
        #pragma unroll
        for (int ks = 0; ks < 2; ++ks) {
            s16x8 af[4], bfv[4];
            #pragma unroll
            for (int im = 0; im < 4; ++im)
                af[im] = *reinterpret_cast<const s16x8*>(&As[(wy * 64 + im * 16 + lm) * 72 + ks * 32 + q * 8]);
            #pragma unroll
            for (int in = 0; in < 4; ++in)
                bfv[in] = *reinterpret_cast<const s16x8*>(&Bs[(wx * 64 + in * 16 + lm) * 72 + ks * 32 + q * 8]);
            #pragma unroll
            for (int im = 0; im < 4; ++im)
                #pragma unroll
                for (int in = 0; in < 4; ++in)
                    acc[im][in] = __builtin_amdgcn_mfma_f32_16x16x32_bf16(af[im], bfv[in], acc[im][in], 0, 0, 0);
        }
        __syncthreads();
    }

    if (sel == 2) {
        #pragma unroll
        for (int in = 0; in < 4; ++in) {
            const int gcol = n0 + wx * 64 + in * 16 + lm;
            const float bv = bias[gcol];
            #pragma unroll
            for (int im = 0; im < 4; ++im) {
                const int grow0 = m0 + wy * 64 + im * 16 + q * 4;
                #pragma unroll
                for (int r = 0; r < 4; ++r) {
                    const float val = acc[im][in][r] + bv;
                    const int grow = grow0 + r;
                    const int bb = grow >> 11, s = grow & (SEQn - 1);
                    const int hh = gcol >> 7,  d = gcol & (HDn - 1);
                    Vt[(((size_t)(bb * NHn + hh)) * HDn + d) * SEQn + s] = f2bf(val);
                }
            }
        }
    } else {
        ushort* ctile = smem;                  // 128 rows x stride 136
        #pragma unroll
        for (int in = 0; in < 4; ++in) {
            const int col = wx * 64 + in * 16 + lm;
            const float bv = bias[n0 + col];
            #pragma unroll
            for (int im = 0; im < 4; ++im) {
                const int row0 = wy * 64 + im * 16 + q * 4;
                #pragma unroll
                for (int r = 0; r < 4; ++r)
                    ctile[(row0 + r) * 136 + col] = f2bf(acc[im][in][r] + bv);
            }
        }
        __syncthreads();
        ushort* dst = (sel == 0) ? Qb : Kb;
        const int d = tid & 63;
        const float invf = powf(10000.0f, -(float)d * (1.0f / 64.0f));
        for (int r = tid >> 6; r < 128; r += 4) {
            const int s = (m0 + r) & (SEQn - 1);
            const float ang = (float)s * invf;
            const float cs = cosf(ang), sn = sinf(ang);
            const float t1 = bf2f(ctile[r * 136 + d]);
            const float t2 = bf2f(ctile[r * 136 + 64 + d]);
            const size_t base = (size_t)(m0 + r) * DMn + n0 + d;
            dst[base]      = f2bf(t1 * cs - t2 * sn);
            dst[base + 64] = f2bf(t1 * sn + t2 * cs);
        }
    }
}

// ---- final GEMM: out(4096x2048 fp32) = AO(bf16) * WT^T + bias (fp32) -------
// 64(M)x128(N) tile -> 1024 blocks (vs 512 at 128x128): the r9 version ran at
// 2 blocks/CU, too few resident waves to hide barrier drains. Wave tile 32x64,
// acc[2][4]. LDS 27.6 KB.
__global__ __launch_bounds__(256)
void gemm_out_kernel(const ushort* __restrict__ A, const ushort* __restrict__ BT,
                     const float* __restrict__ bias, float* __restrict__ C)
{
    __shared__ __align__(16) ushort As[64 * 72];
    __shared__ __align__(16) ushort Bs[128 * 72];
    const int tid = threadIdx.x;
    const int m0 = blockIdx.y * 64;
    const int n0 = blockIdx.x * 128;
    const int w  = tid >> 6;
    const int l  = tid & 63;
    const int wy = w >> 1, wx = w & 1;
    const int q  = l >> 4, lm = l & 15;

    f32x4 acc[2][4];
    #pragma unroll
    for (int i = 0; i < 2; ++i)
        #pragma unroll
        for (int j = 0; j < 4; ++j) acc[i][j] = (f32x4)0.0f;

    for (int kt = 0; kt < DMn; kt += 64) {
        // 192 rows total (64 A + 128 B) x 8 vec8 = 1536 ids over 256 threads
        #pragma unroll
        for (int it = 0; it < 6; ++it) {
            const int v = tid + it * 256;
            if (it < 2) {                      // v in [0,512): A rows 0..63
                const int r = v >> 3;
                const int c = (v & 7) << 3;
                const uint4 av = *reinterpret_cast<const uint4*>(A + (size_t)(m0 + r) * DMn + kt + c);
                *reinterpret_cast<uint4*>(&As[r * 72 + c]) = av;
            } else {                           // v in [512,1536): B rows 0..127
                const int u = v - 512;
                const int r = u >> 3;
                const int c = (u & 7) << 3;
                const uint4 bv = *reinterpret_cast<const uint4*>(BT + (size_t)(n0 + r) * DMn + kt + c);
                *reinterpret_cast<uint4*>(&Bs[r * 72 + c]) = bv;
            }
        }
        __syncthreads();
        #pragma unroll
        for (int ks = 0; ks < 2; ++ks) {
            s16x8 af[2], bfv[4];
            #pragma unroll
            for (int im = 0; im < 2; ++im)
                af[im] = *reinterpret_cast<const s16x8*>(&As[(wy * 32 + im * 16 + lm) * 72 + ks * 32 + q * 8]);
            #pragma unroll
            for (int in = 0; in < 4; ++in)
                bfv[in] = *reinterpret_cast<const s16x8*>(&Bs[(wx * 64 + in * 16 + lm) * 72 + ks * 32 + q * 8]);
            #pragma unroll
            for (int im = 0; im < 2; ++im)
                #pragma unroll
                for (int in = 0; in < 4; ++in)
                    acc[im][in] = __builtin_amdgcn_mfma_f32_16x16x32_bf16(af[im], bfv[in], acc[im][in], 0, 0, 0);
        }
        __syncthreads();
    }
    #pragma unroll
    for (int in = 0; in < 4; ++in) {
        const int gcol = n0 + wx * 64 + in * 16 + lm;
        const float bv = bias[gcol];
        #pragma unroll
        for (int im = 0; im < 2; ++im) {
            const int grow0 = m0 + wy * 32 + im * 16 + q * 4;
            #pragma unroll
            for (int r = 0; r < 4; ++r)
                C[(size_t)(grow0 + r) * HIDn + gcol] = acc[im][in][r] + bv;
        }
    }
}

// -------- MFMA flash attention (round-4 version, measured 90 us) ------------
__global__ __launch_bounds__(256)
void attn_mfma_kernel(const ushort* Q, const ushort* __restrict__ K,
                      const ushort* __restrict__ Vt, const float* __restrict__ kw,
                      ushort* AO)
{
    __shared__ ushort plds[4][16 * 40];   // per-wave P tile, stride 40 (2-way = free)
    const int w  = threadIdx.x >> 6;
    const int l  = threadIdx.x & 63;
    const int q  = l >> 4, lm = l & 15;
    const int gw = blockIdx.x * 4 + w;     // b(1) | h(4) | qt(7)
    const int qt = gw & 127;
    const int h  = (gw >> 7) & (NHn - 1);
    const int b  = gw >> 11;
    const int q0 = qt * 16;
    const float f = kw[h] * 0.08838834764831845f;   // kw * HD^-0.5

    s16x8 qf[4];
    const size_t qbase = ((size_t)(b * SEQn + q0 + lm)) * DMn + h * HDn;
    #pragma unroll
    for (int ks = 0; ks < 4; ++ks)
        qf[ks] = *reinterpret_cast<const s16x8*>(Q + qbase + ks * 32 + q * 8);

    f32x4 O[8];
    #pragma unroll
    for (int nt = 0; nt < 8; ++nt) O[nt] = (f32x4)0.0f;
    float m[4]    = {-1e30f, -1e30f, -1e30f, -1e30f};
    float lsum[4] = {0.f, 0.f, 0.f, 0.f};

    const int lo = q0 - WINn;
    const int c0 = lo > 0 ? (lo & ~31) : 0;
    const int nch = (q0 + 16 - c0 + 31) >> 5;

    const size_t kbh = ((size_t)(b * SEQn)) * DMn + h * HDn;
    const size_t vbh = ((size_t)(b * NHn + h)) * HDn * SEQn;

    for (int c = 0; c < nch; ++c) {
        const int kc = c0 + c * 32;
        f32x4 S[2];
        #pragma unroll
        for (int t = 0; t < 2; ++t) {
            f32x4 acc = (f32x4)0.0f;
            const size_t krow = kbh + (size_t)(kc + t * 16 + lm) * DMn;
            #pragma unroll
            for (int ks = 0; ks < 4; ++ks) {
                const s16x8 kf = *reinterpret_cast<const s16x8*>(K + krow + ks * 32 + q * 8);
                acc = __builtin_amdgcn_mfma_f32_16x16x32_bf16(qf[ks], kf, acc, 0, 0, 0);
            }
            S[t] = acc;
        }
        const int j0 = kc + lm, j1 = kc + 16 + lm;
        #pragma unroll
        for (int r = 0; r < 4; ++r) {
            const int i = q0 + q * 4 + r;
            float v0 = S[0][r] * f;
            float v1 = S[1][r] * f;
            if (j0 > i || j0 < i - WINn) v0 = -1e30f;
            if (j1 > i || j1 < i - WINn) v1 = -1e30f;
            float mx = fmaxf(v0, v1);
            #pragma unroll
            for (int off = 8; off > 0; off >>= 1)
                mx = fmaxf(mx, __shfl_xor(mx, off));
            const float mn = fmaxf(m[r], mx);
            const float alpha = __expf(m[r] - mn);
            m[r] = mn;
            const ushort h0 = f2bf(__expf(v0 - mn));
            const ushort h1 = f2bf(__expf(v1 - mn));
            plds[w][(q * 4 + r) * 40 + lm]      = h0;
            plds[w][(q * 4 + r) * 40 + 16 + lm] = h1;
            float ps = bf2f(h0) + bf2f(h1);
            #pragma unroll
            for (int off = 8; off > 0; off >>= 1)
                ps += __shfl_xor(ps, off);
            lsum[r] = lsum[r] * alpha + ps;
            #pragma unroll
            for (int nt = 0; nt < 8; ++nt) O[nt][r] *= alpha;
        }
        const s16x8 pf = *reinterpret_cast<const s16x8*>(&plds[w][lm * 40 + q * 8]);
        #pragma unroll
        for (int nt = 0; nt < 8; ++nt) {
            const s16x8 vf = *reinterpret_cast<const s16x8*>(
                Vt + vbh + (size_t)(nt * 16 + lm) * SEQn + kc + q * 8);
            O[nt] = __builtin_amdgcn_mfma_f32_16x16x32_bf16(pf, vf, O[nt], 0, 0, 0);
        }
    }
    #pragma unroll
    for (int r = 0; r < 4; ++r) {
        const float inv = 1.0f / lsum[r];
        const size_t orow = ((size_t)(b * SEQn + q0 + q * 4 + r)) * DMn + h * HDn;
        #pragma unroll
        for (int nt = 0; nt < 8; ++nt)
            AO[orow + nt * 16 + lm] = f2bf(O[nt][r] * inv);
    }
}

extern "C" void kernel_launch(void* const* d_in, const int* in_sizes, int n_in,
                              void* d_out, int out_size, void* d_ws, size_t ws_size,
                              hipStream_t stream)
{
    (void)in_sizes; (void)n_in; (void)out_size;
    const float* x  = (const float*)d_in[0];
    const float* WQ = (const float*)d_in[1];
    const float* bQ = (const float*)d_in[2];
    const float* WK = (const float*)d_in[3];
    const float* bK = (const float*)d_in[4];
    const float* WV = (const float*)d_in[5];
    const float* bV = (const float*)d_in[6];
    const float* WO = (const float*)d_in[7];
    const float* bO = (const float*)d_in[8];
    const float* kw = (const float*)d_in[9];
    float* out = (float*)d_out;

    // Workspace: Qb/Kb/Vt bf16 (16 MB each) + WT 3 slabs (24 MB) = 72 MB;
    // + optional xb (16 MB) = 88 MB when ws_size permits (confirmed working r7/r9).
    char* ws = (char*)d_ws;
    const size_t AELEMS = (size_t)MROWS * DMn;         // 4096*2048
    ushort* Qb = (ushort*)ws;                          // also AO (in-place)
    ushort* Kb = (ushort*)(ws + AELEMS * 2);
    ushort* Vt = (ushort*)(ws + AELEMS * 4);           // [b][h][d][s]
    ushort* WT = (ushort*)(ws + AELEMS * 6);           // 3 x 2048x2048 bf16
    ushort* xb = (ushort*)(ws + AELEMS * 6 + WELEMS * 6);
    const bool have_xb = ws_size >= (size_t)(AELEMS * 6 + WELEMS * 6) + AELEMS * 2;

    const dim3 tblk(32, 8);

    if (have_xb) {
        // z=0..2: weight transposes; z=3: x -> xb convert (fused)
        transpose_qkv_kernel<<<dim3(64, 64, 4), tblk, 0, stream>>>(WQ, WK, WV, WT, x, xb);
        gemm_qkv_kernel<1><<<dim3(3 * DMn / 128, MROWS / 128), 256, 0, stream>>>(
            xb, WT, bQ, bK, bV, Qb, Kb, Vt);
    } else {
        transpose_qkv_kernel<<<dim3(64, 64, 3), tblk, 0, stream>>>(WQ, WK, WV, WT, x, xb);
        gemm_qkv_kernel<0><<<dim3(3 * DMn / 128, MROWS / 128), 256, 0, stream>>>(
            x, WT, bQ, bK, bV, Qb, Kb, Vt);
    }

    attn_mfma_kernel<<<dim3(BATCHn * NHn * (SEQn / 16) / 4), 256, 0, stream>>>(Qb, Kb, Vt, kw, Qb);

    transpose_cvt_kernel<<<dim3(64, 64), tblk, 0, stream>>>(WO, WT);
    gemm_out_kernel<<<dim3(HIDn / 128, MROWS / 64), 256, 0, stream>>>(Qb, WT, bO, out);
}

// Round 11
// 428.627 us; speedup vs baseline: 1.9423x; 1.0068x over previous
//
#include <hip/hip_runtime.h>
#include <cstdint>

#define SEQn   2048
#define NHn    16
#define HDn    128
#define DMn    2048   // NH*HD
#define HIDn   2048
#define BATCHn 2
#define WINn   256
#define MROWS  (BATCHn*SEQn)  // 4096
#define WELEMS ((size_t)HIDn * DMn)

typedef short s16x8 __attribute__((ext_vector_type(8)));  // 8 bf16 (4 VGPRs)
typedef float f32x4 __attribute__((ext_vector_type(4)));  // MFMA accumulator

__device__ __forceinline__ float bf2f(ushort x) {
    union { uint u; float f; } v; v.u = ((uint)x) << 16; return v.f;
}
__device__ __forceinline__ ushort f2bf(float f) {
    union { float f; uint u; } v; v.f = f;
    uint u = v.u;
    return (ushort)((u + 0x7FFFu + ((u >> 16) & 1u)) >> 16);  // RNE
}

// --- ONE up-front dispatch: z=0..3 transpose {WQ,WK,WV,WO} -> WT slabs,
//     z=4: x fp32 -> bf16 (removes the mid-pipeline transpose serialization) --
__global__ __launch_bounds__(256)
void transpose_all_kernel(const float* __restrict__ WQ, const float* __restrict__ WK,
                          const float* __restrict__ WV, const float* __restrict__ WO,
                          ushort* __restrict__ WT,
                          const float* __restrict__ x, ushort* __restrict__ xb)
{
    const int tid = threadIdx.y * 32 + threadIdx.x;
    if (blockIdx.z == 4) {
        const int bid = blockIdx.y * 64 + blockIdx.x;
        const size_t base = ((size_t)bid * 256 + tid) * 8;
        const float4 a0 = *reinterpret_cast<const float4*>(x + base);
        const float4 a1 = *reinterpret_cast<const float4*>(x + base + 4);
        ushort4 o0, o1;
        o0.x = f2bf(a0.x); o0.y = f2bf(a0.y); o0.z = f2bf(a0.z); o0.w = f2bf(a0.w);
        o1.x = f2bf(a1.x); o1.y = f2bf(a1.y); o1.z = f2bf(a1.z); o1.w = f2bf(a1.w);
        *reinterpret_cast<ushort4*>(xb + base)     = o0;
        *reinterpret_cast<ushort4*>(xb + base + 4) = o1;
        return;
    }
    __shared__ ushort t[32][33];
    const float* src = (blockIdx.z == 0) ? WQ : (blockIdx.z == 1) ? WK
                     : (blockIdx.z == 2) ? WV : WO;
    ushort* dst = WT + (size_t)blockIdx.z * WELEMS;
    const int tx = threadIdx.x, ty = threadIdx.y;
    const int n  = blockIdx.x * 32 + tx;
    const int k0 = blockIdx.y * 32;
    #pragma unroll
    for (int r = ty; r < 32; r += 8)
        t[r][tx] = f2bf(src[(size_t)(k0 + r) * 2048 + n]);
    __syncthreads();
    const int k  = k0 + tx;
    const int nb = blockIdx.x * 32;
    #pragma unroll
    for (int r = ty; r < 32; r += 8)
        dst[(size_t)(nb + r) * 2048 + k] = t[tx][r];
}

// ------- single transpose+convert (fallback path only) -----------------------
__global__ __launch_bounds__(256)
void transpose_cvt_kernel(const float* __restrict__ src, ushort* __restrict__ dst)
{
    __shared__ ushort t[32][33];
    const int tx = threadIdx.x, ty = threadIdx.y;
    const int n  = blockIdx.x * 32 + tx;
    const int k0 = blockIdx.y * 32;
    #pragma unroll
    for (int r = ty; r < 32; r += 8)
        t[r][tx] = f2bf(src[(size_t)(k0 + r) * 2048 + n]);
    __syncthreads();
    const int k  = k0 + tx;
    const int nb = blockIdx.x * 32;
    #pragma unroll
    for (int r = ty; r < 32; r += 8)
        dst[(size_t)(nb + r) * 2048 + k] = t[tx][r];
}

// -------- fused QKV GEMM + fused RoPE epilogue (round-9 measured: 170 us) ---
template<int ABF16>
__global__ __launch_bounds__(256)
void gemm_qkv_kernel(const void* __restrict__ Araw, const ushort* __restrict__ WT,
                     const float* __restrict__ bQ, const float* __restrict__ bK,
                     const float* __restrict__ bV,
                     ushort* __restrict__ Qb, ushort* __restrict__ Kb,
                     ushort* __restrict__ Vt)
{
    __shared__ __align__(16) ushort smem[2 * 128 * 72];   // As | Bs; reused as ctile
    ushort* As = smem;
    ushort* Bs = smem + 128 * 72;
    const int tid = threadIdx.x;
    const int m0  = blockIdx.y * 128;
    const int n0g = blockIdx.x * 128;          // 0..6143
    const int sel = n0g >> 11;                 // 0=Q 1=K 2=V
    const int n0  = n0g & 2047;
    const ushort* BT  = WT + (size_t)sel * WELEMS;
    const float* bias = (sel == 0) ? bQ : (sel == 1) ? bK : bV;
    const int w  = tid >> 6;
    const int l  = tid & 63;
    const int wy = w >> 1, wx = w & 1;
    const int q  = l >> 4, lm = l & 15;

    f32x4 acc[4][4];
    #pragma unroll
    for (int i = 0; i < 4; ++i)
        #pragma unroll
        for (int j = 0; j < 4; ++j) acc[i][j] = (f32x4)0.0f;

    for (int kt = 0; kt < HIDn; kt += 64) {
        #pragma unroll
        for (int it = 0; it < 4; ++it) {
            const int v = tid + it * 256;
            const int r = v >> 3;
            const int c = (v & 7) << 3;
            if (ABF16) {
                const uint4 av = *reinterpret_cast<const uint4*>(
                    (const ushort*)Araw + (size_t)(m0 + r) * HIDn + kt + c);
                *reinterpret_cast<uint4*>(&As[r * 72 + c]) = av;
            } else {
                const float* Af = (const float*)Araw + (size_t)(m0 + r) * HIDn + kt + c;
                const float4 a0 = *reinterpret_cast<const float4*>(Af);
                const float4 a1 = *reinterpret_cast<const float4*>(Af + 4);
                ushort* d = &As[r * 72 + c];
                d[0] = f2bf(a0.x); d[1] = f2bf(a0.y); d[2] = f2bf(a0.z); d[3] = f2bf(a0.w);
                d[4] = f2bf(a1.x); d[5] = f2bf(a1.y); d[6] = f2bf(a1.z); d[7] = f2bf(a1.w);
            }
            const uint4 bv = *reinterpret_cast<const uint4*>(BT + (size_t)(n0 + r) * HIDn + kt + c);
            *reinterpret_cast<uint4*>(&Bs[r * 72 + c]) = bv;
        }
        __syncthreads();
        #pragma unroll
        for (int ks = 0; ks < 2; ++ks) {
            s16x8 af[4], bfv[4];
            #pragma unroll
            for (int im = 0; im < 4; ++im)
                af[im] = *reinterpret_cast<const s16x8*>(&As[(wy * 64 + im * 16 + lm) * 72 + ks * 32 + q * 8]);
            #pragma unroll
            for (int in = 0; in < 4; ++in)
                bfv[in] = *reinterpret_cast<const s16x8*>(&Bs[(wx * 64 + in * 16 + lm) * 72 + ks * 32 + q * 8]);
            #pragma unroll
            for (int im = 0; im < 4; ++im)
                #pragma unroll
                for (int in = 0; in < 4; ++in)
                    acc[im][in] = __builtin_amdgcn_mfma_f32_16x16x32_bf16(af[im], bfv[in], acc[im][in], 0, 0, 0);
        }
        __syncthreads();
    }

    if (sel == 2) {
        #pragma unroll
        for (int in = 0; in < 4; ++in) {
            const int gcol = n0 + wx * 64 + in * 16 + lm;
            const float bv = bias[gcol];
            #pragma unroll
            for (int im = 0; im < 4; ++im) {
                const int grow0 = m0 + wy * 64 + im * 16 + q * 4;
                #pragma unroll
                for (int r = 0; r < 4; ++r) {
                    const float val = acc[im][in][r] + bv;
                    const int grow = grow0 + r;
                    const int bb = grow >> 11, s = grow & (SEQn - 1);
                    const int hh = gcol >> 7,  d = gcol & (HDn - 1);
                    Vt[(((size_t)(bb * NHn + hh)) * HDn + d) * SEQn + s] = f2bf(val);
                }
            }
        }
    } else {
        ushort* ctile = smem;                  // 128 rows x stride 136
        #pragma unroll
        for (int in = 0; in < 4; ++in) {
            const int col = wx * 64 + in * 16 + lm;
            const float bv = bias[n0 + col];
            #pragma unroll
            for (int im = 0; im < 4; ++im) {
                const int row0 = wy * 64 + im * 16 + q * 4;
                #pragma unroll
                for (int r = 0; r < 4; ++r)
                    ctile[(row0 + r) * 136 + col] = f2bf(acc[im][in][r] + bv);
            }
        }
        __syncthreads();
        ushort* dst = (sel == 0) ? Qb : Kb;
        const int d = tid & 63;
        const float invf = powf(10000.0f, -(float)d * (1.0f / 64.0f));
        for (int r = tid >> 6; r < 128; r += 4) {
            const int s = (m0 + r) & (SEQn - 1);
            const float ang = (float)s * invf;
            const float cs = cosf(ang), sn = sinf(ang);
            const float t1 = bf2f(ctile[r * 136 + d]);
            const float t2 = bf2f(ctile[r * 136 + 64 + d]);
            const size_t base = (size_t)(m0 + r) * DMn + n0 + d;
            dst[base]      = f2bf(t1 * cs - t2 * sn);
            dst[base + 64] = f2bf(t1 * sn + t2 * cs);
        }
    }
}

// ---- final GEMM: out(4096x2048 fp32) = AO(bf16) * WT^T + bias (fp32) -------
// 64(M)x128(N) tile, 1024 blocks (measured equal to 128x128; kept).
__global__ __launch_bounds__(256)
void gemm_out_kernel(const ushort* __restrict__ A, const ushort* __restrict__ BT,
                     const float* __restrict__ bias, float* __restrict__ C)
{
    __shared__ __align__(16) ushort As[64 * 72];
    __shared__ __align__(16) ushort Bs[128 * 72];
    const int tid = threadIdx.x;
    const int m0 = blockIdx.y * 64;
    const int n0 = blockIdx.x * 128;
    const int w  = tid >> 6;
    const int l  = tid & 63;
    const int wy = w >> 1, wx = w & 1;
    const int q  = l >> 4, lm = l & 15;

    f32x4 acc[2][4];
    #pragma unroll
    for (int i = 0; i < 2; ++i)
        #pragma unroll
        for (int j = 0; j < 4; ++j) acc[i][j] = (f32x4)0.0f;

    for (int kt = 0; kt < DMn; kt += 64) {
        #pragma unroll
        for (int it = 0; it < 6; ++it) {
            const int v = tid + it * 256;
            if (it < 2) {                      // A rows 0..63
                const int r = v >> 3;
                const int c = (v & 7) << 3;
                const uint4 av = *reinterpret_cast<const uint4*>(A + (size_t)(m0 + r) * DMn + kt + c);
                *reinterpret_cast<uint4*>(&As[r * 72 + c]) = av;
            } else {                           // B rows 0..127
                const int u = v - 512;
                const int r = u >> 3;
                const int c = (u & 7) << 3;
                const uint4 bv = *reinterpret_cast<const uint4*>(BT + (size_t)(n0 + r) * DMn + kt + c);
                *reinterpret_cast<uint4*>(&Bs[r * 72 + c]) = bv;
            }
        }
        __syncthreads();
        #pragma unroll
        for (int ks = 0; ks < 2; ++ks) {
            s16x8 af[2], bfv[4];
            #pragma unroll
            for (int im = 0; im < 2; ++im)
                af[im] = *reinterpret_cast<const s16x8*>(&As[(wy * 32 + im * 16 + lm) * 72 + ks * 32 + q * 8]);
            #pragma unroll
            for (int in = 0; in < 4; ++in)
                bfv[in] = *reinterpret_cast<const s16x8*>(&Bs[(wx * 64 + in * 16 + lm) * 72 + ks * 32 + q * 8]);
            #pragma unroll
            for (int im = 0; im < 2; ++im)
                #pragma unroll
                for (int in = 0; in < 4; ++in)
                    acc[im][in] = __builtin_amdgcn_mfma_f32_16x16x32_bf16(af[im], bfv[in], acc[im][in], 0, 0, 0);
        }
        __syncthreads();
    }
    #pragma unroll
    for (int in = 0; in < 4; ++in) {
        const int gcol = n0 + wx * 64 + in * 16 + lm;
        const float bv = bias[gcol];
        #pragma unroll
        for (int im = 0; im < 2; ++im) {
            const int grow0 = m0 + wy * 32 + im * 16 + q * 4;
            #pragma unroll
            for (int r = 0; r < 4; ++r)
                C[(size_t)(grow0 + r) * HIDn + gcol] = acc[im][in][r] + bv;
        }
    }
}

// -------- MFMA flash attention: r4 structure + V-prefetch -------------------
// 4 waves/block, one (b,h,16-query tile) per wave. The 8 Vt frag loads are
// hoisted to chunk start (independent of softmax) so their latency overlaps
// QK^T + softmax instead of stalling the PV MFMAs. NOT loop-carried (r8
// spill lesson): +32 VGPRs live intra-iteration only, stays under the
// 128-VGPR / 4-wave-per-SIMD cliff.
__global__ __launch_bounds__(256)
void attn_mfma_kernel(const ushort* Q, const ushort* __restrict__ K,
                      const ushort* __restrict__ Vt, const float* __restrict__ kw,
                      ushort* AO)
{
    __shared__ ushort plds[4][16 * 40];   // per-wave P tile, stride 40 (2-way = free)
    const int w  = threadIdx.x >> 6;
    const int l  = threadIdx.x & 63;
    const int q  = l >> 4, lm = l & 15;
    const int gw = blockIdx.x * 4 + w;     // b(1) | h(4) | qt(7)
    const int qt = gw & 127;
    const int h  = (gw >> 7) & (NHn - 1);
    const int b  = gw >> 11;
    const int q0 = qt * 16;
    const float f = kw[h] * 0.08838834764831845f;   // kw * HD^-0.5

    s16x8 qf[4];
    const size_t qbase = ((size_t)(b * SEQn + q0 + lm)) * DMn + h * HDn;
    #pragma unroll
    for (int ks = 0; ks < 4; ++ks)
        qf[ks] = *reinterpret_cast<const s16x8*>(Q + qbase + ks * 32 + q * 8);

    f32x4 O[8];
    #pragma unroll
    for (int nt = 0; nt < 8; ++nt) O[nt] = (f32x4)0.0f;
    float m[4]    = {-1e30f, -1e30f, -1e30f, -1e30f};
    float lsum[4] = {0.f, 0.f, 0.f, 0.f};

    const int lo = q0 - WINn;
    const int c0 = lo > 0 ? (lo & ~31) : 0;
    const int nch = (q0 + 16 - c0 + 31) >> 5;

    const size_t kbh = ((size_t)(b * SEQn)) * DMn + h * HDn;
    const size_t vbh = ((size_t)(b * NHn + h)) * HDn * SEQn;

    for (int c = 0; c < nch; ++c) {
        const int kc = c0 + c * 32;
        // ---- prefetch V frags (independent of softmax) ----
        s16x8 vf[8];
        #pragma unroll
        for (int nt = 0; nt < 8; ++nt)
            vf[nt] = *reinterpret_cast<const s16x8*>(
                Vt + vbh + (size_t)(nt * 16 + lm) * SEQn + kc + q * 8);
        // ---- QK^T: two 16-key tiles, 4 chained k-MFMAs each ----
        f32x4 S[2];
        #pragma unroll
        for (int t = 0; t < 2; ++t) {
            f32x4 acc = (f32x4)0.0f;
            const size_t krow = kbh + (size_t)(kc + t * 16 + lm) * DMn;
            #pragma unroll
            for (int ks = 0; ks < 4; ++ks) {
                const s16x8 kf = *reinterpret_cast<const s16x8*>(K + krow + ks * 32 + q * 8);
                acc = __builtin_amdgcn_mfma_f32_16x16x32_bf16(qf[ks], kf, acc, 0, 0, 0);
            }
            S[t] = acc;
        }
        // ---- scale, mask, online softmax ----
        const int j0 = kc + lm, j1 = kc + 16 + lm;
        #pragma unroll
        for (int r = 0; r < 4; ++r) {
            const int i = q0 + q * 4 + r;
            float v0 = S[0][r] * f;
            float v1 = S[1][r] * f;
            if (j0 > i || j0 < i - WINn) v0 = -1e30f;
            if (j1 > i || j1 < i - WINn) v1 = -1e30f;
            float mx = fmaxf(v0, v1);
            #pragma unroll
            for (int off = 8; off > 0; off >>= 1)
                mx = fmaxf(mx, __shfl_xor(mx, off));
            const float mn = fmaxf(m[r], mx);
            const float alpha = __expf(m[r] - mn);
            m[r] = mn;
            const ushort h0 = f2bf(__expf(v0 - mn));
            const ushort h1 = f2bf(__expf(v1 - mn));
            plds[w][(q * 4 + r) * 40 + lm]      = h0;
            plds[w][(q * 4 + r) * 40 + 16 + lm] = h1;
            float ps = bf2f(h0) + bf2f(h1);
            #pragma unroll
            for (int off = 8; off > 0; off >>= 1)
                ps += __shfl_xor(ps, off);
            lsum[r] = lsum[r] * alpha + ps;
            #pragma unroll
            for (int nt = 0; nt < 8; ++nt) O[nt][r] *= alpha;
        }
        // ---- P -> A-frag via per-wave LDS round trip; P·V ----
        const s16x8 pf = *reinterpret_cast<const s16x8*>(&plds[w][lm * 40 + q * 8]);
        #pragma unroll
        for (int nt = 0; nt < 8; ++nt)
            O[nt] = __builtin_amdgcn_mfma_f32_16x16x32_bf16(pf, vf[nt], O[nt], 0, 0, 0);
    }
    #pragma unroll
    for (int r = 0; r < 4; ++r) {
        const float inv = 1.0f / lsum[r];
        const size_t orow = ((size_t)(b * SEQn + q0 + q * 4 + r)) * DMn + h * HDn;
        #pragma unroll
        for (int nt = 0; nt < 8; ++nt)
            AO[orow + nt * 16 + lm] = f2bf(O[nt][r] * inv);
    }
}

extern "C" void kernel_launch(void* const* d_in, const int* in_sizes, int n_in,
                              void* d_out, int out_size, void* d_ws, size_t ws_size,
                              hipStream_t stream)
{
    (void)in_sizes; (void)n_in; (void)out_size;
    const float* x  = (const float*)d_in[0];
    const float* WQ = (const float*)d_in[1];
    const float* bQ = (const float*)d_in[2];
    const float* WK = (const float*)d_in[3];
    const float* bK = (const float*)d_in[4];
    const float* WV = (const float*)d_in[5];
    const float* bV = (const float*)d_in[6];
    const float* WO = (const float*)d_in[7];
    const float* bO = (const float*)d_in[8];
    const float* kw = (const float*)d_in[9];
    float* out = (float*)d_out;

    // Full path: Qb/Kb/Vt (48 MB) + WT 4 slabs (32 MB) + xb (16 MB) = 96 MB.
    // Fallback (ws < 96 MB): 3 slabs, fp32-A QKV GEMM, late WO transpose.
    char* ws = (char*)d_ws;
    const size_t AELEMS = (size_t)MROWS * DMn;         // 4096*2048
    ushort* Qb = (ushort*)ws;                          // also AO (in-place)
    ushort* Kb = (ushort*)(ws + AELEMS * 2);
    ushort* Vt = (ushort*)(ws + AELEMS * 4);           // [b][h][d][s]
    ushort* WT = (ushort*)(ws + AELEMS * 6);           // up to 4 x 2048x2048 bf16
    const size_t FULL = AELEMS * 6 + WELEMS * 8 + AELEMS * 2;   // 96 MB
    const bool have_full = ws_size >= FULL;
    ushort* xb = (ushort*)(ws + AELEMS * 6 + WELEMS * 8);

    const dim3 tblk(32, 8);

    if (have_full) {
        transpose_all_kernel<<<dim3(64, 64, 5), tblk, 0, stream>>>(WQ, WK, WV, WO, WT, x, xb);
        gemm_qkv_kernel<1><<<dim3(3 * DMn / 128, MROWS / 128), 256, 0, stream>>>(
            xb, WT, bQ, bK, bV, Qb, Kb, Vt);
        attn_mfma_kernel<<<dim3(BATCHn * NHn * (SEQn / 16) / 4), 256, 0, stream>>>(Qb, Kb, Vt, kw, Qb);
        gemm_out_kernel<<<dim3(HIDn / 128, MROWS / 64), 256, 0, stream>>>(
            Qb, WT + 3 * WELEMS, bO, out);
    } else {
        transpose_all_kernel<<<dim3(64, 64, 3), tblk, 0, stream>>>(WQ, WK, WV, WO, WT, x, xb);
        gemm_qkv_kernel<0><<<dim3(3 * DMn / 128, MROWS / 128), 256, 0, stream>>>(
            x, WT, bQ, bK, bV, Qb, Kb, Vt);
        attn_mfma_kernel<<<dim3(BATCHn * NHn * (SEQn / 16) / 4), 256, 0, stream>>>(Qb, Kb, Vt, kw, Qb);
        transpose_cvt_kernel<<<dim3(64, 64), tblk, 0, stream>>>(WO, WT);
        gemm_out_kernel<<<dim3(HIDn / 128, MROWS / 64), 256, 0, stream>>>(Qb, WT, bO, out);
    }
}